// Round 1
// baseline (252.783 us; speedup 1.0000x reference)
//
#include <hip/hip_runtime.h>

// CARAFE: B=4, C=128, H=W=64, C_MID=64, S=2, K=5
#define HW    4096   // 64*64
#define C_IN  128
#define C_MID 64
#define NB    4

// workspace layout (float offsets)
#define OFF_W1T 0           // 128*64         = 8192
#define OFF_W2T 8192        // 4*64*9*25      = 57600
#define OFF_H   65792       // 4*64*4096      = 1048576
#define OFF_KER 1114368     // 4*64*100*64    = 1638400
// total floats = 2752768 (~10.5 MB)

// ---------------- prep: transpose w1 and w2 for scalar-load-friendly layouts ----------------
__global__ __launch_bounds__(256) void prep_kernel(const float* __restrict__ w1,
                                                   const float* __restrict__ w2,
                                                   float* __restrict__ ws) {
    int tid = blockIdx.x * 256 + threadIdx.x;
    if (tid < 8192) {
        // w1t[c][o] = w1[o][c]
        int o = tid & 63, c = tid >> 6;
        ws[OFF_W1T + c * 64 + o] = w1[o * 128 + c];
    } else if (tid < 65792) {
        // w2t[((g*64+c)*9+t)*25 + wi] = w2[((g*25+wi)*64+c)*9 + t]
        int i = tid - 8192;
        int wi = i % 25;
        int r  = i / 25;
        int t  = r % 9;
        int r2 = r / 9;
        int c  = r2 & 63;
        int g  = r2 >> 6;
        ws[OFF_W2T + i] = w2[(((g * 25 + wi) * 64 + c) * 9) + t];
    }
}

// ---------------- k1: 1x1 conv + BN + ReLU -> h[b][o][pix] ----------------
__global__ __launch_bounds__(256) void k1_pointwise(const float* __restrict__ x,
                                                    const float* __restrict__ ws,
                                                    const float* __restrict__ gamma,
                                                    const float* __restrict__ beta,
                                                    const float* __restrict__ mean,
                                                    const float* __restrict__ var,
                                                    float* __restrict__ h_out) {
    int p  = blockIdx.x * 256 + threadIdx.x;   // global pixel over B*H*W
    int b  = p >> 12;
    int pp = p & 4095;
    int oq = blockIdx.y;                        // output quad: o = oq*4 + j
    const float* w1t = ws + OFF_W1T;

    float a0 = 0.f, a1 = 0.f, a2 = 0.f, a3 = 0.f;
    const float* xb = x + (size_t)b * C_IN * HW + pp;
    #pragma unroll 4
    for (int c = 0; c < C_IN; ++c) {
        float xv = xb[(size_t)c * HW];
        const float4 w = *(const float4*)(w1t + c * 64 + oq * 4);  // wave-uniform -> s_load
        a0 = fmaf(w.x, xv, a0);
        a1 = fmaf(w.y, xv, a1);
        a2 = fmaf(w.z, xv, a2);
        a3 = fmaf(w.w, xv, a3);
    }
    float acc[4] = {a0, a1, a2, a3};
    #pragma unroll
    for (int j = 0; j < 4; ++j) {
        int o = oq * 4 + j;
        float inv = gamma[o] * rsqrtf(var[o] + 1e-5f);
        float add = beta[o] - mean[o] * inv;
        float v = fmaxf(fmaf(acc[j], inv, add), 0.f);
        h_out[((size_t)b * C_MID + o) * HW + pp] = v;
    }
}

// ---------------- k2: 3x3 conv (64 -> 100) + softmax over 25 taps ----------------
// grid: 256 blocks = (b, 8x8 tile of 8x8 pixels); block: 256 thr = 4 waves (wave g = softmax group)
__global__ __launch_bounds__(256) void k2_conv_softmax(float* __restrict__ ws) {
    __shared__ float hs[6400];  // [c][y*10+x], 10x10 halo tile
    int b    = blockIdx.x >> 6;
    int tile = blockIdx.x & 63;
    int ty0 = (tile >> 3) << 3;
    int tx0 = (tile & 7) << 3;

    const float* hbase = ws + OFF_H + (size_t)b * C_MID * HW;
    for (int idx = threadIdx.x; idx < 6400; idx += 256) {
        int c = idx / 100;
        int r = idx - c * 100;
        int y = r / 10;
        int xq = r - y * 10;
        int gy = ty0 + y - 1, gx = tx0 + xq - 1;
        float v = 0.f;
        if ((unsigned)gy < 64u && (unsigned)gx < 64u)
            v = hbase[(size_t)c * HW + gy * 64 + gx];
        hs[idx] = v;
    }
    __syncthreads();

    int g   = __builtin_amdgcn_readfirstlane((int)(threadIdx.x >> 6));  // wave-uniform group
    int pix = threadIdx.x & 63;
    int py  = pix >> 3, px = pix & 7;

    float acc[25];
    #pragma unroll
    for (int i = 0; i < 25; ++i) acc[i] = 0.f;

    const float* w2g = ws + OFF_W2T + g * 14400;  // [c][tap][25]
    for (int c = 0; c < C_MID; ++c) {
        const float* hc = hs + c * 100 + py * 10 + px;
        const float* wc = w2g + c * 225;
        #pragma unroll
        for (int ky = 0; ky < 3; ++ky) {
            #pragma unroll
            for (int kx = 0; kx < 3; ++kx) {
                float hv = hc[ky * 10 + kx];
                const float* wp = wc + (ky * 3 + kx) * 25;  // uniform -> s_load
                #pragma unroll
                for (int wi = 0; wi < 25; ++wi)
                    acc[wi] = fmaf(hv, wp[wi], acc[wi]);
            }
        }
    }

    // in-thread softmax over 25 taps
    float m = acc[0];
    #pragma unroll
    for (int i = 1; i < 25; ++i) m = fmaxf(m, acc[i]);
    float ssum = 0.f;
    #pragma unroll
    for (int i = 0; i < 25; ++i) { acc[i] = __expf(acc[i] - m); ssum += acc[i]; }
    float rs = 1.f / ssum;

    // ker[(b*64+tile)][q=t*4+g][pix] -- coalesced stores (lanes = pix)
    float* kbase = ws + OFF_KER + (size_t)blockIdx.x * 6400;
    #pragma unroll
    for (int t = 0; t < 25; ++t)
        kbase[(t * 4 + g) * 64 + pix] = acc[t] * rs;
}

// ---------------- k3: 5x5 reassembly + pixel shuffle ----------------
// grid: (256 tiles, 4 ch-quarters); block: 256 thr = 64 pixels x 4 waves; wave handles 8 channels
__global__ __launch_bounds__(256) void k3_reassemble(const float* __restrict__ x,
                                                     const float* __restrict__ ws,
                                                     float* __restrict__ out) {
    __shared__ float ks[6400];  // [q=t*4+g][pix]
    int b    = blockIdx.x >> 6;
    int tile = blockIdx.x & 63;
    int ty0 = (tile >> 3) << 3;
    int tx0 = (tile & 7) << 3;

    const float* kbase = ws + OFF_KER + (size_t)blockIdx.x * 6400;
    for (int idx = threadIdx.x; idx < 6400; idx += 256) ks[idx] = kbase[idx];
    __syncthreads();

    int wave = threadIdx.x >> 6;
    int pix  = threadIdx.x & 63;
    int py = pix >> 3, px = pix & 7;
    int Y = ty0 + py, X = tx0 + px;
    int ch0 = blockIdx.y * 32 + wave * 8;

    float acc[32];  // [8 ch][4 g]
    #pragma unroll
    for (int i = 0; i < 32; ++i) acc[i] = 0.f;

    const float* xb = x + ((size_t)b * C_IN + ch0) * HW;
    #pragma unroll
    for (int t = 0; t < 25; ++t) {
        int ti = t / 5, tj = t % 5;
        int yy = Y + ti - 2, xx = X + tj - 2;
        bool ok = ((unsigned)yy < 64u) && ((unsigned)xx < 64u);
        float k0 = ks[(t * 4 + 0) * 64 + pix];
        float k1 = ks[(t * 4 + 1) * 64 + pix];
        float k2 = ks[(t * 4 + 2) * 64 + pix];
        float k3 = ks[(t * 4 + 3) * 64 + pix];
        int off = yy * 64 + xx;
        #pragma unroll
        for (int i = 0; i < 8; ++i) {
            float xv = ok ? xb[(size_t)i * HW + off] : 0.f;
            acc[i * 4 + 0] = fmaf(xv, k0, acc[i * 4 + 0]);
            acc[i * 4 + 1] = fmaf(xv, k1, acc[i * 4 + 1]);
            acc[i * 4 + 2] = fmaf(xv, k2, acc[i * 4 + 2]);
            acc[i * 4 + 3] = fmaf(xv, k3, acc[i * 4 + 3]);
        }
    }

    // pixel shuffle: g=(si,sj): out[b][ch][2Y+si][2X+sj]
    #pragma unroll
    for (int i = 0; i < 8; ++i) {
        size_t o0 = (((size_t)b * C_IN + ch0 + i) * 128 + 2 * Y) * 128 + 2 * X;
        float2 r0 = make_float2(acc[i * 4 + 0], acc[i * 4 + 1]);
        float2 r1 = make_float2(acc[i * 4 + 2], acc[i * 4 + 3]);
        *(float2*)(out + o0)        = r0;   // row 2Y:   (g0, g1)
        *(float2*)(out + o0 + 128)  = r1;   // row 2Y+1: (g2, g3)
    }
}

extern "C" void kernel_launch(void* const* d_in, const int* in_sizes, int n_in,
                              void* d_out, int out_size, void* d_ws, size_t ws_size,
                              hipStream_t stream) {
    const float* x     = (const float*)d_in[0];
    const float* w1    = (const float*)d_in[1];
    const float* w2    = (const float*)d_in[2];
    const float* gamma = (const float*)d_in[3];
    const float* beta  = (const float*)d_in[4];
    const float* mean  = (const float*)d_in[5];
    const float* var   = (const float*)d_in[6];
    float* out = (float*)d_out;
    float* ws  = (float*)d_ws;

    prep_kernel<<<257, 256, 0, stream>>>(w1, w2, ws);
    k1_pointwise<<<dim3(64, 16), 256, 0, stream>>>(x, ws, gamma, beta, mean, var, ws + OFF_H);
    k2_conv_softmax<<<256, 256, 0, stream>>>(ws);
    k3_reassemble<<<dim3(256, 4), 256, 0, stream>>>(x, ws, out);
}

// Round 2
// 157.068 us; speedup vs baseline: 1.6094x; 1.6094x over previous
//
#include <hip/hip_runtime.h>
#include <hip/hip_bf16.h>

// CARAFE: B=4, C=128, H=W=64, C_MID=64, S=2, K=5
#define HW    4096
#define C_IN  128
#define C_MID 64

typedef __attribute__((ext_vector_type(8))) short  short8;   // 8 bf16 (4 VGPRs)
typedef __attribute__((ext_vector_type(4))) float  floatx4;  // MFMA C/D

// workspace layout (BYTE offsets)
#define OFF_W1T 0ul        // float[128*64]            = 32768 B
#define OFF_W2B 32768ul    // bf16 [112*576]           = 129024 B
#define OFF_H   161792ul   // bf16 [4*4096*64]         = 2097152 B
#define OFF_KER 2258944ul  // float[4*64*100*64]       = 6553600 B  (end ~8.8 MB)

// ---------------- prep: w1 transpose (fp32) + w2 -> bf16 [n][k] with k = tap*64 + c ----------
__global__ __launch_bounds__(256) void prep_kernel(const float* __restrict__ w1,
                                                   const float* __restrict__ w2,
                                                   char* __restrict__ ws) {
    int tid = blockIdx.x * 256 + threadIdx.x;
    if (tid < 8192) {
        // w1t[c][o] = w1[o][c]
        int o = tid & 63, c = tid >> 6;
        ((float*)(ws + OFF_W1T))[c * 64 + o] = w1[o * 128 + c];
    } else if (tid < 8192 + 112 * 576) {
        int i = tid - 8192;
        int n = i / 576;          // 0..111 (100..111 zero pad)
        int k = i - n * 576;      // k = t*64 + c
        int t = k >> 6, c = k & 63;
        float v = (n < 100) ? w2[(n * 64 + c) * 9 + t] : 0.f;
        ((__hip_bfloat16*)(ws + OFF_W2B))[i] = __float2bfloat16(v);
    }
}

// ---------------- k1: 1x1 conv + BN + ReLU -> h bf16 [b][pix][c] ----------------
// grid (64, 4): thread = 1 pixel x 16 outputs
__global__ __launch_bounds__(256) void k1_pointwise(const float* __restrict__ x,
                                                    char* __restrict__ ws,
                                                    const float* __restrict__ gamma,
                                                    const float* __restrict__ beta,
                                                    const float* __restrict__ mean,
                                                    const float* __restrict__ var) {
    int p  = blockIdx.x * 256 + threadIdx.x;   // global pixel over B*H*W
    int b  = p >> 12;
    int pp = p & 4095;
    int o0 = blockIdx.y * 16;
    const float* w1t = (const float*)(ws + OFF_W1T);

    float acc[16];
    #pragma unroll
    for (int j = 0; j < 16; ++j) acc[j] = 0.f;

    const float* xb = x + (size_t)b * C_IN * HW + pp;
    #pragma unroll 4
    for (int c = 0; c < C_IN; ++c) {
        float xv = xb[(size_t)c * HW];
        const float* wr = w1t + c * 64 + o0;   // wave-uniform -> s_load
        #pragma unroll
        for (int j = 0; j < 16; ++j) acc[j] = fmaf(wr[j], xv, acc[j]);
    }

    union { uint4 v; __hip_bfloat16 h[8]; } u0, u1;
    #pragma unroll
    for (int j = 0; j < 16; ++j) {
        int o = o0 + j;
        float inv = gamma[o] * rsqrtf(var[o] + 1e-5f);
        float add = beta[o] - mean[o] * inv;
        float v = fmaxf(fmaf(acc[j], inv, add), 0.f);
        if (j < 8) u0.h[j] = __float2bfloat16(v); else u1.h[j - 8] = __float2bfloat16(v);
    }
    __hip_bfloat16* hout = (__hip_bfloat16*)(ws + OFF_H) + ((size_t)(b * 4096 + pp)) * 64 + o0;
    *(uint4*)(hout)     = u0.v;
    *(uint4*)(hout + 8) = u1.v;
}

// ---------------- k2: 3x3 conv (64->100) as bf16 MFMA GEMM + fused softmax ----------------
// GEMM: [16384 pix] x [K=576 (tap*64+c)] x [N=112 (100 + pad)]
// grid: 256 blocks = (b, 8x8 tile of 8x8 pixels); 4 waves; wave = 16-pixel M-subtile, 7 N-tiles
__global__ __launch_bounds__(256) void k2_conv_softmax(char* __restrict__ ws) {
    __shared__ __hip_bfloat16 hs[100 * 88];  // [halo pix][c], row stride 88 (16B-aligned, 2-way banks)
    __shared__ float lg[64 * 113];           // logits [pix][n], stride 113 (conflict-free)

    int b    = blockIdx.x >> 6;
    int tile = blockIdx.x & 63;
    int ty0 = (tile >> 3) << 3;
    int tx0 = (tile & 7) << 3;

    // ---- stage h halo tile (10x10 pixels x 64 c, bf16) ----
    const __hip_bfloat16* hglob = (const __hip_bfloat16*)(ws + OFF_H) + (size_t)b * 4096 * 64;
    #pragma unroll
    for (int pass = 0; pass < 4; ++pass) {
        int r = pass * 32 + (threadIdx.x >> 3);
        if (r < 100) {
            int hy = r / 10, hx = r - hy * 10;
            int gy = ty0 + hy - 1, gx = tx0 + hx - 1;
            int ch = (threadIdx.x & 7) * 8;
            uint4 v = make_uint4(0u, 0u, 0u, 0u);
            if ((unsigned)gy < 64u && (unsigned)gx < 64u)
                v = *(const uint4*)(hglob + (size_t)(gy * 64 + gx) * 64 + ch);
            *(uint4*)(&hs[r * 88 + ch]) = v;
        }
    }
    __syncthreads();

    int lane = threadIdx.x & 63, wave = threadIdx.x >> 6;
    int q = lane >> 4, m = lane & 15;
    int pixidx = wave * 16 + m;            // A-operand row m = lane&15
    int py = pixidx >> 3, px = pixidx & 7;

    const __hip_bfloat16* w2b = (const __hip_bfloat16*)(ws + OFF_W2B);
    const __hip_bfloat16* bp  = w2b + (size_t)m * 576 + q * 8;  // B row n=f*16+m, k-chunk q*8

    floatx4 acc[7];
    #pragma unroll
    for (int f = 0; f < 7; ++f)
        #pragma unroll
        for (int r = 0; r < 4; ++r) acc[f][r] = 0.f;

    short8 bcur[7];
    #pragma unroll
    for (int f = 0; f < 7; ++f) bcur[f] = *(const short8*)(bp + f * 9216);

    for (int s = 0; s < 18; ++s) {
        int t = s >> 1, c0 = (s & 1) * 32;
        short8 a = *(const short8*)(&hs[((py + t / 3) * 10 + (px + t % 3)) * 88 + c0 + q * 8]);
        short8 bnx[7];
        if (s < 17) {
            int ko = (s + 1) * 32;
            #pragma unroll
            for (int f = 0; f < 7; ++f) bnx[f] = *(const short8*)(bp + f * 9216 + ko);
        }
        #pragma unroll
        for (int f = 0; f < 7; ++f)
            acc[f] = __builtin_amdgcn_mfma_f32_16x16x32_bf16(a, bcur[f], acc[f], 0, 0, 0);
        if (s < 17) {
            #pragma unroll
            for (int f = 0; f < 7; ++f) bcur[f] = bnx[f];
        }
    }

    // ---- dump logits to LDS: C/D layout col=lane&15, row=(lane>>4)*4+reg ----
    #pragma unroll
    for (int f = 0; f < 7; ++f)
        #pragma unroll
        for (int r = 0; r < 4; ++r)
            lg[(wave * 16 + q * 4 + r) * 113 + f * 16 + m] = acc[f][r];
    __syncthreads();

    // ---- per-thread softmax over 25 taps: thread = (pixel, group) ----
    int g   = threadIdx.x >> 6;
    int pix = threadIdx.x & 63;
    float v[25];
    #pragma unroll
    for (int wi = 0; wi < 25; ++wi) v[wi] = lg[pix * 113 + g * 25 + wi];
    float mx = v[0];
    #pragma unroll
    for (int wi = 1; wi < 25; ++wi) mx = fmaxf(mx, v[wi]);
    float ssum = 0.f;
    #pragma unroll
    for (int wi = 0; wi < 25; ++wi) { v[wi] = __expf(v[wi] - mx); ssum += v[wi]; }
    float rs = 1.f / ssum;

    float* kbase = (float*)(ws + OFF_KER) + (size_t)blockIdx.x * 6400;
    #pragma unroll
    for (int t25 = 0; t25 < 25; ++t25)
        kbase[(t25 * 4 + g) * 64 + pix] = v[t25] * rs;
}

// ---------------- k3: 5x5 reassembly + pixel shuffle ----------------
__global__ __launch_bounds__(256) void k3_reassemble(const float* __restrict__ x,
                                                     const char* __restrict__ ws,
                                                     float* __restrict__ out) {
    __shared__ float ks[6400];  // [q=t*4+g][pix]
    int b    = blockIdx.x >> 6;
    int tile = blockIdx.x & 63;
    int ty0 = (tile >> 3) << 3;
    int tx0 = (tile & 7) << 3;

    const float* kbase = (const float*)(ws + OFF_KER) + (size_t)blockIdx.x * 6400;
    for (int idx = threadIdx.x; idx < 6400; idx += 256) ks[idx] = kbase[idx];
    __syncthreads();

    int wave = threadIdx.x >> 6;
    int pix  = threadIdx.x & 63;
    int py = pix >> 3, px = pix & 7;
    int Y = ty0 + py, X = tx0 + px;
    int ch0 = blockIdx.y * 32 + wave * 8;

    float acc[32];  // [8 ch][4 g]
    #pragma unroll
    for (int i = 0; i < 32; ++i) acc[i] = 0.f;

    const float* xb = x + ((size_t)b * C_IN + ch0) * HW;
    #pragma unroll
    for (int t = 0; t < 25; ++t) {
        int ti = t / 5, tj = t % 5;
        int yy = Y + ti - 2, xx = X + tj - 2;
        bool ok = ((unsigned)yy < 64u) && ((unsigned)xx < 64u);
        float k0 = ks[(t * 4 + 0) * 64 + pix];
        float k1 = ks[(t * 4 + 1) * 64 + pix];
        float k2 = ks[(t * 4 + 2) * 64 + pix];
        float k3 = ks[(t * 4 + 3) * 64 + pix];
        int off = yy * 64 + xx;
        #pragma unroll
        for (int i = 0; i < 8; ++i) {
            float xv = ok ? xb[(size_t)i * HW + off] : 0.f;
            acc[i * 4 + 0] = fmaf(xv, k0, acc[i * 4 + 0]);
            acc[i * 4 + 1] = fmaf(xv, k1, acc[i * 4 + 1]);
            acc[i * 4 + 2] = fmaf(xv, k2, acc[i * 4 + 2]);
            acc[i * 4 + 3] = fmaf(xv, k3, acc[i * 4 + 3]);
        }
    }

    #pragma unroll
    for (int i = 0; i < 8; ++i) {
        size_t o0 = (((size_t)b * C_IN + ch0 + i) * 128 + 2 * Y) * 128 + 2 * X;
        *(float2*)(out + o0)       = make_float2(acc[i * 4 + 0], acc[i * 4 + 1]);
        *(float2*)(out + o0 + 128) = make_float2(acc[i * 4 + 2], acc[i * 4 + 3]);
    }
}

extern "C" void kernel_launch(void* const* d_in, const int* in_sizes, int n_in,
                              void* d_out, int out_size, void* d_ws, size_t ws_size,
                              hipStream_t stream) {
    const float* x     = (const float*)d_in[0];
    const float* w1    = (const float*)d_in[1];
    const float* w2    = (const float*)d_in[2];
    const float* gamma = (const float*)d_in[3];
    const float* beta  = (const float*)d_in[4];
    const float* mean  = (const float*)d_in[5];
    const float* var   = (const float*)d_in[6];
    float* out = (float*)d_out;
    char*  ws  = (char*)d_ws;

    prep_kernel<<<284, 256, 0, stream>>>(w1, w2, ws);
    k1_pointwise<<<dim3(64, 4), 256, 0, stream>>>(x, ws, gamma, beta, mean, var);
    k2_conv_softmax<<<256, 256, 0, stream>>>(ws);
    k3_reassemble<<<dim3(256, 4), 256, 0, stream>>>(x, ws, out);
}

// Round 3
// 148.540 us; speedup vs baseline: 1.7018x; 1.0574x over previous
//
#include <hip/hip_runtime.h>
#include <hip/hip_bf16.h>

// CARAFE: B=4, C=128, H=W=64, C_MID=64, S=2, K=5
#define HW    4096
#define C_IN  128
#define C_MID 64

typedef __attribute__((ext_vector_type(8))) short  short8;   // 8 bf16 (4 VGPRs)
typedef __attribute__((ext_vector_type(4))) float  floatx4;  // MFMA C/D

// workspace layout (BYTE offsets)
#define OFF_W1T 0ul        // float[128*64]            = 32768 B
#define OFF_W2B 32768ul    // bf16 [112*576]           = 129024 B
#define OFF_H   161792ul   // bf16 [4*4096*64]         = 2097152 B
#define OFF_KER 2258944ul  // float[4*64*100*64]       = 6553600 B  (end ~8.8 MB)

// ---------------- prep: w1 transpose (fp32) + w2 -> bf16 [n][k] with k = tap*64 + c ----------
__global__ __launch_bounds__(256) void prep_kernel(const float* __restrict__ w1,
                                                   const float* __restrict__ w2,
                                                   char* __restrict__ ws) {
    int tid = blockIdx.x * 256 + threadIdx.x;
    if (tid < 8192) {
        int o = tid & 63, c = tid >> 6;
        ((float*)(ws + OFF_W1T))[c * 64 + o] = w1[o * 128 + c];
    } else if (tid < 8192 + 112 * 576) {
        int i = tid - 8192;
        int n = i / 576;          // 0..111 (100..111 zero pad)
        int k = i - n * 576;      // k = t*64 + c
        int t = k >> 6, c = k & 63;
        float v = (n < 100) ? w2[(n * 64 + c) * 9 + t] : 0.f;
        ((__hip_bfloat16*)(ws + OFF_W2B))[i] = __float2bfloat16(v);
    }
}

// ---------------- k1: 1x1 conv + BN + ReLU -> h bf16 [b][pix][c] ----------------
// grid 256: block = 64 consecutive pixels; x tile staged in LDS; wave computes 16 outputs
__global__ __launch_bounds__(256) void k1_pointwise(const float* __restrict__ x,
                                                    char* __restrict__ ws,
                                                    const float* __restrict__ gamma,
                                                    const float* __restrict__ beta,
                                                    const float* __restrict__ mean,
                                                    const float* __restrict__ var) {
    __shared__ float xs[128 * 64];   // [c][i], 32 KB
    int b   = blockIdx.x >> 6;
    int pp0 = (blockIdx.x & 63) * 64;

    const float* xb = x + (size_t)b * C_IN * HW + pp0;
    for (int idx = threadIdx.x; idx < 8192; idx += 256) {
        int c = idx >> 6, i = idx & 63;
        xs[idx] = xb[(size_t)c * HW + i];
    }
    __syncthreads();

    int wave = threadIdx.x >> 6, pix = threadIdx.x & 63;
    int o0 = wave * 16;
    const float* w1t = (const float*)(ws + OFF_W1T);

    float acc[16];
    #pragma unroll
    for (int j = 0; j < 16; ++j) acc[j] = 0.f;

    for (int c = 0; c < C_IN; ++c) {
        float xv = xs[c * 64 + pix];
        const float* wr = w1t + c * 64 + o0;   // wave-uniform -> s_load
        #pragma unroll
        for (int j = 0; j < 16; ++j) acc[j] = fmaf(wr[j], xv, acc[j]);
    }

    union { uint4 v; __hip_bfloat16 h[8]; } u0, u1;
    #pragma unroll
    for (int j = 0; j < 16; ++j) {
        int o = o0 + j;
        float inv = gamma[o] * rsqrtf(var[o] + 1e-5f);
        float add = beta[o] - mean[o] * inv;
        float v = fmaxf(fmaf(acc[j], inv, add), 0.f);
        if (j < 8) u0.h[j] = __float2bfloat16(v); else u1.h[j - 8] = __float2bfloat16(v);
    }
    __hip_bfloat16* hout = (__hip_bfloat16*)(ws + OFF_H) + ((size_t)(b * 4096 + pp0 + pix)) * 64 + o0;
    *(uint4*)(hout)     = u0.v;
    *(uint4*)(hout + 8) = u1.v;
}

// ---------------- k2: 3x3 conv (64->100) as bf16 MFMA GEMM + fused softmax ----------------
__global__ __launch_bounds__(256) void k2_conv_softmax(char* __restrict__ ws) {
    __shared__ __hip_bfloat16 hs[100 * 88];  // [halo pix][c], row stride 88
    __shared__ float lg[64 * 113];           // logits [pix][n], stride 113

    int b    = blockIdx.x >> 6;
    int tile = blockIdx.x & 63;
    int ty0 = (tile >> 3) << 3;
    int tx0 = (tile & 7) << 3;

    const __hip_bfloat16* hglob = (const __hip_bfloat16*)(ws + OFF_H) + (size_t)b * 4096 * 64;
    #pragma unroll
    for (int pass = 0; pass < 4; ++pass) {
        int r = pass * 32 + (threadIdx.x >> 3);
        if (r < 100) {
            int hy = r / 10, hx = r - hy * 10;
            int gy = ty0 + hy - 1, gx = tx0 + hx - 1;
            int ch = (threadIdx.x & 7) * 8;
            uint4 v = make_uint4(0u, 0u, 0u, 0u);
            if ((unsigned)gy < 64u && (unsigned)gx < 64u)
                v = *(const uint4*)(hglob + (size_t)(gy * 64 + gx) * 64 + ch);
            *(uint4*)(&hs[r * 88 + ch]) = v;
        }
    }
    __syncthreads();

    int lane = threadIdx.x & 63, wave = threadIdx.x >> 6;
    int q = lane >> 4, m = lane & 15;
    int pixidx = wave * 16 + m;
    int py = pixidx >> 3, px = pixidx & 7;

    const __hip_bfloat16* w2b = (const __hip_bfloat16*)(ws + OFF_W2B);
    const __hip_bfloat16* bp  = w2b + (size_t)m * 576 + q * 8;

    floatx4 acc[7];
    #pragma unroll
    for (int f = 0; f < 7; ++f)
        #pragma unroll
        for (int r = 0; r < 4; ++r) acc[f][r] = 0.f;

    short8 bcur[7];
    #pragma unroll
    for (int f = 0; f < 7; ++f) bcur[f] = *(const short8*)(bp + f * 9216);

    for (int s = 0; s < 18; ++s) {
        int t = s >> 1, c0 = (s & 1) * 32;
        short8 a = *(const short8*)(&hs[((py + t / 3) * 10 + (px + t % 3)) * 88 + c0 + q * 8]);
        short8 bnx[7];
        if (s < 17) {
            int ko = (s + 1) * 32;
            #pragma unroll
            for (int f = 0; f < 7; ++f) bnx[f] = *(const short8*)(bp + f * 9216 + ko);
        }
        #pragma unroll
        for (int f = 0; f < 7; ++f)
            acc[f] = __builtin_amdgcn_mfma_f32_16x16x32_bf16(a, bcur[f], acc[f], 0, 0, 0);
        if (s < 17) {
            #pragma unroll
            for (int f = 0; f < 7; ++f) bcur[f] = bnx[f];
        }
    }

    #pragma unroll
    for (int f = 0; f < 7; ++f)
        #pragma unroll
        for (int r = 0; r < 4; ++r)
            lg[(wave * 16 + q * 4 + r) * 113 + f * 16 + m] = acc[f][r];
    __syncthreads();

    int g   = threadIdx.x >> 6;
    int pix = threadIdx.x & 63;
    float v[25];
    #pragma unroll
    for (int wi = 0; wi < 25; ++wi) v[wi] = lg[pix * 113 + g * 25 + wi];
    float mx = v[0];
    #pragma unroll
    for (int wi = 1; wi < 25; ++wi) mx = fmaxf(mx, v[wi]);
    float ssum = 0.f;
    #pragma unroll
    for (int wi = 0; wi < 25; ++wi) { v[wi] = __expf(v[wi] - mx); ssum += v[wi]; }
    float rs = 1.f / ssum;

    float* kbase = (float*)(ws + OFF_KER) + (size_t)blockIdx.x * 6400;
    #pragma unroll
    for (int t25 = 0; t25 < 25; ++t25)
        kbase[(t25 * 4 + g) * 64 + pix] = v[t25] * rs;
}

// ---------------- k3: 5x5 reassembly + pixel shuffle, x staged in LDS ----------------
// grid (256 tiles, 4 ch-quarters); block: 64 pixels x 4 waves; wave = 8 channels
__global__ __launch_bounds__(256) void k3_reassemble(const float* __restrict__ x,
                                                     const char* __restrict__ ws,
                                                     float* __restrict__ out) {
    __shared__ float ks[6400];        // [q=t*4+g][pix]
    __shared__ float xs[32 * 144];    // [c][p], p = hy*12+hx (12x12 halo, zero-padded)

    int b    = blockIdx.x >> 6;
    int tile = blockIdx.x & 63;
    int ty0 = (tile >> 3) << 3;
    int tx0 = (tile & 7) << 3;
    int ch0 = blockIdx.y * 32;

    const float* kbase = (const float*)(ws + OFF_KER) + (size_t)blockIdx.x * 6400;
    for (int idx = threadIdx.x; idx < 6400; idx += 256) ks[idx] = kbase[idx];

    const float* xb = x + ((size_t)b * C_IN + ch0) * HW;
    for (int idx = threadIdx.x; idx < 4608; idx += 256) {
        int c = idx / 144;
        int p = idx - c * 144;
        int hy = p / 12, hx = p - hy * 12;
        int gy = ty0 + hy - 2, gx = tx0 + hx - 2;
        float v = 0.f;
        if ((unsigned)gy < 64u && (unsigned)gx < 64u)
            v = xb[(size_t)c * HW + gy * 64 + gx];
        xs[idx] = v;
    }
    __syncthreads();

    int wave = threadIdx.x >> 6;
    int pix  = threadIdx.x & 63;
    int py = pix >> 3, px = pix & 7;
    int Y = ty0 + py, X = tx0 + px;

    float acc[32];  // [8 ch][4 g]
    #pragma unroll
    for (int i = 0; i < 32; ++i) acc[i] = 0.f;

    const float* xw = xs + wave * 8 * 144 + py * 12 + px;  // bank-free: 2 lanes/bank
    #pragma unroll 5
    for (int t = 0; t < 25; ++t) {
        int ti = t / 5, tj = t % 5;
        int po = ti * 12 + tj;
        float k0 = ks[(t * 4 + 0) * 64 + pix];
        float k1 = ks[(t * 4 + 1) * 64 + pix];
        float k2 = ks[(t * 4 + 2) * 64 + pix];
        float k3 = ks[(t * 4 + 3) * 64 + pix];
        #pragma unroll
        for (int i = 0; i < 8; ++i) {
            float xv = xw[i * 144 + po];
            acc[i * 4 + 0] = fmaf(xv, k0, acc[i * 4 + 0]);
            acc[i * 4 + 1] = fmaf(xv, k1, acc[i * 4 + 1]);
            acc[i * 4 + 2] = fmaf(xv, k2, acc[i * 4 + 2]);
            acc[i * 4 + 3] = fmaf(xv, k3, acc[i * 4 + 3]);
        }
    }

    int ch = ch0 + wave * 8;
    #pragma unroll
    for (int i = 0; i < 8; ++i) {
        size_t o0 = (((size_t)b * C_IN + ch + i) * 128 + 2 * Y) * 128 + 2 * X;
        *(float2*)(out + o0)       = make_float2(acc[i * 4 + 0], acc[i * 4 + 1]);
        *(float2*)(out + o0 + 128) = make_float2(acc[i * 4 + 2], acc[i * 4 + 3]);
    }
}

extern "C" void kernel_launch(void* const* d_in, const int* in_sizes, int n_in,
                              void* d_out, int out_size, void* d_ws, size_t ws_size,
                              hipStream_t stream) {
    const float* x     = (const float*)d_in[0];
    const float* w1    = (const float*)d_in[1];
    const float* w2    = (const float*)d_in[2];
    const float* gamma = (const float*)d_in[3];
    const float* beta  = (const float*)d_in[4];
    const float* mean  = (const float*)d_in[5];
    const float* var   = (const float*)d_in[6];
    float* out = (float*)d_out;
    char*  ws  = (char*)d_ws;

    prep_kernel<<<284, 256, 0, stream>>>(w1, w2, ws);
    k1_pointwise<<<256, 256, 0, stream>>>(x, ws, gamma, beta, mean, var);
    k2_conv_softmax<<<256, 256, 0, stream>>>(ws);
    k3_reassemble<<<dim3(256, 4), 256, 0, stream>>>(x, ws, out);
}